// Round 2
// baseline (3160.026 us; speedup 1.0000x reference)
//
#include <hip/hip_runtime.h>
#include <stdint.h>

typedef unsigned long long u64;

#define D_      256
#define K_      1024
#define N_      131072
#define MARGIN  0.024f

using short8 = __attribute__((ext_vector_type(8))) short;
using f32x4  = __attribute__((ext_vector_type(4))) float;

__device__ __forceinline__ unsigned short f2bf(float f) {
    unsigned int x = __float_as_uint(f);
    return (unsigned short)((x + 0x7fffu + ((x >> 16) & 1u)) >> 16);
}
__device__ __forceinline__ float sqr_rn(float x) { return __fmul_rn(x, x); }

// numpy pairwise sum of squares over 256 elements (identical to round-1's passing code)
__device__ __forceinline__ float np_pairwise_sq_256(const float* p) {
    float tot[2];
#pragma unroll
    for (int blk = 0; blk < 2; ++blk) {
        const float* q = p + blk * 128;
        float r[8];
#pragma unroll
        for (int j = 0; j < 8; ++j) r[j] = sqr_rn(q[j]);
        for (int i = 8; i < 128; i += 8) {
#pragma unroll
            for (int j = 0; j < 8; ++j) r[j] = __fadd_rn(r[j], sqr_rn(q[i + j]));
        }
        tot[blk] = __fadd_rn(__fadd_rn(__fadd_rn(r[0], r[1]), __fadd_rn(r[2], r[3])),
                             __fadd_rn(__fadd_rn(r[4], r[5]), __fadd_rn(r[6], r[7])));
    }
    return __fadd_rn(tot[0], tot[1]);
}

// ---------------- prep: esq (np-pairwise, exact f32) + Eh (bf16 copy of E) ----------------
__global__ __launch_bounds__(64)
void prep_kernel(const float* __restrict__ E, float* __restrict__ esq,
                 unsigned short* __restrict__ Eh) {
    int code = blockIdx.x * 64 + threadIdx.x;
    const float* row = E + (size_t)code * D_;
    unsigned short* hrow = Eh + (size_t)code * D_;
    for (int d = 0; d < D_; ++d) hrow[d] = f2bf(row[d]);
    esq[code] = np_pairwise_sq_256(row);
}

// ---------------- main: bf16 MFMA approx scores + per-row candidate collection + gather ----
// block: 128 rows x 1024 codes (4 code-tiles of 256). 512 threads = 8 waves (2 row x 4 col),
// wave tile 64x64 via 4x4 frags of mfma_f32_16x16x32_bf16.
// LDS layout (dynamic, 105984 B):
//   zh   [128][256] bf16, byte-swizzled:  addr = row*512 + (byte ^ ((row&7)<<4))
//   et   [256][64]  bf16, byte-swizzled:  addr = code*128 + (byte ^ ((code&7)<<4))
//   part float[4][128], rowmin float[128], thr float[128], cnt uint[128], cand uint[128][8]
__global__ __launch_bounds__(512, 2)
void vq_main(const float* __restrict__ Z, const unsigned short* __restrict__ Eh,
             const float* __restrict__ esq_g, const float* __restrict__ E,
             unsigned int* __restrict__ cnt_g, unsigned int* __restrict__ cand_g,
             float* __restrict__ out) {
    extern __shared__ char smem[];
    char*  zhb    = smem;                       // 65536
    char*  etb    = smem + 65536;               // 32768
    float* part   = (float*)(smem + 98304);     // 4*128*4 = 2048
    float* rowmin = (float*)(smem + 100352);    // 512
    float* thr    = (float*)(smem + 100864);    // 512
    unsigned int* cnt  = (unsigned int*)(smem + 101376);  // 512
    unsigned int* cand = (unsigned int*)(smem + 101888);  // 128*8*4 = 4096

    const int t    = threadIdx.x;
    const int lane = t & 63;
    const int wv   = t >> 6;
    const int wr   = wv >> 2;       // 0..1  (row half)
    const int wc   = wv & 3;        // 0..3  (code quarter)
    const int col  = lane & 15;     // MFMA col / frag row-index
    const int g    = lane >> 4;     // 0..3
    const int r0   = blockIdx.x * 128;

    if (t < 128) { rowmin[t] = 3.0e38f; cnt[t] = 0u; }

    // ---- stage z tile: 128 rows x 256 d, f32 -> bf16, swizzled ----
    const float4* Z4 = (const float4*)(Z + (size_t)r0 * D_);
#pragma unroll
    for (int q = 0; q < 16; ++q) {
        int idx = t + 512 * q;              // 0..8191
        int row = idx >> 6, c4 = idx & 63;  // 64 float4 per row
        float4 v = Z4[(size_t)row * 64 + c4];
        unsigned int lo = (unsigned int)f2bf(v.x) | ((unsigned int)f2bf(v.y) << 16);
        unsigned int hi = (unsigned int)f2bf(v.z) | ((unsigned int)f2bf(v.w) << 16);
        int boff = (c4 * 8) ^ ((row & 7) << 4);
        *(uint2*)(zhb + row * 512 + boff) = make_uint2(lo, hi);
    }
    __syncthreads();

    const uint4* EhC = (const uint4*)Eh;    // 16B chunks; 32 chunks per code row
    const int asw = (lane & 7) << 4;        // == (A-row&7)<<4 == (B-code&7)<<4

    for (int ct = 0; ct < 4; ++ct) {
        const int c0 = ct * 256;
        float esqv[4];
#pragma unroll
        for (int cf = 0; cf < 4; ++cf)
            esqv[cf] = esq_g[c0 + wc * 64 + cf * 16 + col];

        f32x4 acc[4][4];
#pragma unroll
        for (int rf = 0; rf < 4; ++rf)
#pragma unroll
            for (int cf = 0; cf < 4; ++cf) acc[rf][cf] = (f32x4){0.f, 0.f, 0.f, 0.f};

        for (int dc = 0; dc < 4; ++dc) {
            // stage E tile: 256 codes x 64 d (bf16), swizzled
#pragma unroll
            for (int q = 0; q < 4; ++q) {
                int idx  = t + 512 * q;           // 0..2047
                int code = idx >> 3, ch = idx & 7;
                uint4 v = EhC[(size_t)(c0 + code) * 32 + dc * 8 + ch];
                *(uint4*)(etb + code * 128 + ((ch * 16) ^ ((code & 7) << 4))) = v;
            }
            __syncthreads();

#pragma unroll
            for (int j = 0; j < 2; ++j) {
                const int kb  = dc * 128 + j * 64 + g * 16;   // byte off in zh row
                const int kbl = j * 64 + g * 16;              // byte off in et row
                short8 a[4], b[4];
#pragma unroll
                for (int rf = 0; rf < 4; ++rf) {
                    int row = wr * 64 + rf * 16 + col;
                    a[rf] = *(const short8*)(zhb + row * 512 + (kb ^ asw));
                }
#pragma unroll
                for (int cf = 0; cf < 4; ++cf) {
                    int code = wc * 64 + cf * 16 + col;
                    b[cf] = *(const short8*)(etb + code * 128 + (kbl ^ asw));
                }
#pragma unroll
                for (int rf = 0; rf < 4; ++rf)
#pragma unroll
                    for (int cf = 0; cf < 4; ++cf)
                        acc[rf][cf] = __builtin_amdgcn_mfma_f32_16x16x32_bf16(
                            a[rf], b[cf], acc[rf][cf], 0, 0, 0);
            }
            __syncthreads();
        }

        // ---- epilogue: s = esq - 2*cross ; per-row min ; candidate append ----
#pragma unroll
        for (int rf = 0; rf < 4; ++rf)
#pragma unroll
            for (int cf = 0; cf < 4; ++cf)
#pragma unroll
                for (int i = 0; i < 4; ++i)
                    acc[rf][cf][i] = fmaf(-2.0f, acc[rf][cf][i], esqv[cf]);

#pragma unroll
        for (int rf = 0; rf < 4; ++rf)
#pragma unroll
            for (int i = 0; i < 4; ++i) {
                float m = fminf(fminf(acc[rf][0][i], acc[rf][1][i]),
                                fminf(acc[rf][2][i], acc[rf][3][i]));
                m = fminf(m, __shfl_xor(m, 1, 64));
                m = fminf(m, __shfl_xor(m, 2, 64));
                m = fminf(m, __shfl_xor(m, 4, 64));
                m = fminf(m, __shfl_xor(m, 8, 64));
                if (col == 0) part[wc * 128 + wr * 64 + rf * 16 + g * 4 + i] = m;
            }
        __syncthreads();
        if (t < 128) {
            float m = fminf(fminf(part[0 * 128 + t], part[1 * 128 + t]),
                            fminf(part[2 * 128 + t], part[3 * 128 + t]));
            m = fminf(m, rowmin[t]);
            rowmin[t] = m;
            thr[t] = m + MARGIN;
        }
        __syncthreads();
#pragma unroll
        for (int rf = 0; rf < 4; ++rf)
#pragma unroll
            for (int i = 0; i < 4; ++i) {
                int row = wr * 64 + rf * 16 + g * 4 + i;
                float tv = thr[row];
#pragma unroll
                for (int cf = 0; cf < 4; ++cf) {
                    if (acc[rf][cf][i] <= tv) {
                        unsigned int pos = atomicAdd(&cnt[row], 1u);
                        if (pos < 8u)
                            cand[row * 8 + pos] = (unsigned int)(c0 + wc * 64 + cf * 16 + col);
                    }
                }
            }
        __syncthreads();
    }

    // ---- write out candidate lists + gather (approx winner; resolve fixes flagged rows) ----
    if (t < 128) {
        cnt_g[r0 + t] = cnt[t];
#pragma unroll
        for (int i = 0; i < 8; ++i)
            cand_g[(size_t)(r0 + t) * 8 + i] = cand[t * 8 + i];
    }
    __syncthreads();
    const float4* E4 = (const float4*)E;
    float4* O4 = (float4*)out;
#pragma unroll
    for (int q = 0; q < 16; ++q) {
        int idx = t + 512 * q;
        int row = idx >> 6, f4 = idx & 63;
        unsigned int k = cand[row * 8];
        O4[(size_t)(r0 + row) * 64 + f4] = E4[(size_t)k * 64 + f4];
    }
}

// ---------------- resolve: exact round-1 arithmetic for multi-candidate rows ----------------
__global__ __launch_bounds__(256)
void resolve_kernel(const float* __restrict__ Z, const float* __restrict__ E,
                    const float* __restrict__ esq, const unsigned int* __restrict__ cnt_g,
                    const unsigned int* __restrict__ cand_g, float* __restrict__ out) {
    int r = blockIdx.x * 256 + threadIdx.x;
    unsigned int cnt = cnt_g[r];
    if (cnt <= 1u) return;

    const float* zr = Z + (size_t)r * D_;
    float zs = np_pairwise_sq_256(zr);

    u64 best = ~0ull;
    if (cnt <= 8u) {
        for (unsigned int i = 0; i < cnt; ++i) {
            unsigned int k = cand_g[(size_t)r * 8 + i];
            const float* er = E + (size_t)k * D_;
            float c = 0.f;
            for (int d = 0; d < D_; ++d) c = fmaf(zr[d], er[d], c);
            float dist = __fadd_rn(__fsub_rn(zs, __fmul_rn(2.0f, c)), esq[k]);
            u64 key = ((u64)__float_as_uint(dist) << 32) | (u64)k;
            if (key < best) best = key;
        }
    } else {
        for (unsigned int k = 0; k < (unsigned int)K_; ++k) {
            const float* er = E + (size_t)k * D_;
            float c = 0.f;
            for (int d = 0; d < D_; ++d) c = fmaf(zr[d], er[d], c);
            float dist = __fadd_rn(__fsub_rn(zs, __fmul_rn(2.0f, c)), esq[k]);
            u64 key = ((u64)__float_as_uint(dist) << 32) | (u64)k;
            if (key < best) best = key;
        }
    }
    unsigned int kw = (unsigned int)(best & 0xffffffffu);
    const float4* E4 = (const float4*)E;
    float4* O4 = (float4*)out;
    for (int f4 = 0; f4 < 64; ++f4)
        O4[(size_t)r * 64 + f4] = E4[(size_t)kw * 64 + f4];
}

extern "C" void kernel_launch(void* const* d_in, const int* in_sizes, int n_in,
                              void* d_out, int out_size, void* d_ws, size_t ws_size,
                              hipStream_t stream) {
    const float* Z = (const float*)d_in[0];
    const float* E = (const float*)d_in[1];
    float* out = (float*)d_out;

    // workspace layout (total ~5.2 MB)
    float* esq            = (float*)d_ws;                                   // 4 KB
    unsigned short* Eh    = (unsigned short*)((char*)d_ws + 4096);          // 512 KB
    unsigned int* cnt_g   = (unsigned int*)((char*)d_ws + 4096 + 524288);   // 512 KB
    unsigned int* cand_g  = (unsigned int*)((char*)d_ws + 4096 + 1048576);  // 4 MB

    prep_kernel<<<K_ / 64, 64, 0, stream>>>(E, esq, Eh);

    const int SMEM = 105984;
    hipFuncSetAttribute((const void*)vq_main,
                        hipFuncAttributeMaxDynamicSharedMemorySize, SMEM);
    vq_main<<<N_ / 128, 512, SMEM, stream>>>(Z, Eh, esq, E, cnt_g, cand_g, out);

    resolve_kernel<<<N_ / 256, 256, 0, stream>>>(Z, E, esq, cnt_g, cand_g, out);
}

// Round 3
// 390.143 us; speedup vs baseline: 8.0997x; 8.0997x over previous
//
#include <hip/hip_runtime.h>
#include <stdint.h>

typedef unsigned long long u64;

#define D_      256
#define K_      1024
#define N_      131072
#define MARGIN  0.024f

using short8 = __attribute__((ext_vector_type(8))) short;
using f32x4  = __attribute__((ext_vector_type(4))) float;

__device__ __forceinline__ unsigned short f2bf(float f) {
    unsigned int x = __float_as_uint(f);
    return (unsigned short)((x + 0x7fffu + ((x >> 16) & 1u)) >> 16);
}
__device__ __forceinline__ float sqr_rn(float x) { return __fmul_rn(x, x); }

// numpy pairwise sum of squares over 256 elements (bitwise identical to round-1's passing code)
__device__ __forceinline__ float np_pairwise_sq_256(const float* p) {
    float tot[2];
#pragma unroll
    for (int blk = 0; blk < 2; ++blk) {
        const float* q = p + blk * 128;
        float r[8];
#pragma unroll
        for (int j = 0; j < 8; ++j) r[j] = sqr_rn(q[j]);
        for (int i = 8; i < 128; i += 8) {
#pragma unroll
            for (int j = 0; j < 8; ++j) r[j] = __fadd_rn(r[j], sqr_rn(q[i + j]));
        }
        tot[blk] = __fadd_rn(__fadd_rn(__fadd_rn(r[0], r[1]), __fadd_rn(r[2], r[3])),
                             __fadd_rn(__fadd_rn(r[4], r[5]), __fadd_rn(r[6], r[7])));
    }
    return __fadd_rn(tot[0], tot[1]);
}

// ---------------- prep: esq (np-pairwise f32) + Eh (bf16 copy) + zero flag counter --------
__global__ __launch_bounds__(64)
void prep_kernel(const float* __restrict__ E, float* __restrict__ esq,
                 unsigned short* __restrict__ Eh, unsigned int* __restrict__ flag_cnt) {
    if (blockIdx.x == 0 && threadIdx.x == 0) flag_cnt[0] = 0u;
    int code = blockIdx.x * 64 + threadIdx.x;
    const float* row = E + (size_t)code * D_;
    unsigned short* hrow = Eh + (size_t)code * D_;
    for (int d = 0; d < D_; ++d) hrow[d] = f2bf(row[d]);
    esq[code] = np_pairwise_sq_256(row);
}

// ---------------- main: bf16 MFMA scores, final-pruned candidates, flag or gather ----------
// block: 128 rows x 1024 codes (4 code-tiles of 256). 512 threads = 8 waves (2 row x 4 col).
__global__ __launch_bounds__(512, 2)
void vq_main(const float* __restrict__ Z, const unsigned short* __restrict__ Eh,
             const float* __restrict__ esq_g, const float* __restrict__ E,
             unsigned int* __restrict__ flag_cnt, unsigned int* __restrict__ flag_list,
             unsigned int* __restrict__ cand_g, float* __restrict__ out) {
    extern __shared__ char smem[];
    char*  zhb    = smem;                       // 65536
    char*  etb    = smem + 65536;               // 32768
    float* part   = (float*)(smem + 98304);     // 2048
    float* rowmin = (float*)(smem + 100352);    // 512
    float* thr    = (float*)(smem + 100864);    // 512
    unsigned int* cnt    = (unsigned int*)(smem + 101376);  // 512
    float*        cand_s = (float*)(smem + 101888);         // 128*16*4 = 8192
    unsigned int* cand_i = (unsigned int*)(smem + 110080);  // 8192
    unsigned int* kst    = cnt;  // reuse cnt storage after final prune? NO — need separate
    // use part[] space after it's done? simpler: dedicated kst at end:
    unsigned int* kst2   = (unsigned int*)(smem + 118272);  // 512

    const int t    = threadIdx.x;
    const int lane = t & 63;
    const int wv   = t >> 6;
    const int wr   = wv >> 2;
    const int wc   = wv & 3;
    const int col  = lane & 15;
    const int g    = lane >> 4;
    const int r0   = blockIdx.x * 128;

    if (t < 128) { rowmin[t] = 3.0e38f; cnt[t] = 0u; }

    // ---- stage z tile (f32 -> bf16, swizzled) ----
    const float4* Z4 = (const float4*)(Z + (size_t)r0 * D_);
#pragma unroll
    for (int q = 0; q < 16; ++q) {
        int idx = t + 512 * q;
        int row = idx >> 6, c4 = idx & 63;
        float4 v = Z4[(size_t)row * 64 + c4];
        unsigned int lo = (unsigned int)f2bf(v.x) | ((unsigned int)f2bf(v.y) << 16);
        unsigned int hi = (unsigned int)f2bf(v.z) | ((unsigned int)f2bf(v.w) << 16);
        int boff = (c4 * 8) ^ ((row & 7) << 4);
        *(uint2*)(zhb + row * 512 + boff) = make_uint2(lo, hi);
    }
    __syncthreads();

    const uint4* EhC = (const uint4*)Eh;
    const int asw = (lane & 7) << 4;

    for (int ct = 0; ct < 4; ++ct) {
        const int c0 = ct * 256;
        float esqv[4];
#pragma unroll
        for (int cf = 0; cf < 4; ++cf)
            esqv[cf] = esq_g[c0 + wc * 64 + cf * 16 + col];

        f32x4 acc[4][4];
#pragma unroll
        for (int rf = 0; rf < 4; ++rf)
#pragma unroll
            for (int cf = 0; cf < 4; ++cf) acc[rf][cf] = (f32x4){0.f, 0.f, 0.f, 0.f};

        for (int dc = 0; dc < 4; ++dc) {
#pragma unroll
            for (int q = 0; q < 4; ++q) {
                int idx  = t + 512 * q;
                int code = idx >> 3, ch = idx & 7;
                uint4 v = EhC[(size_t)(c0 + code) * 32 + dc * 8 + ch];
                *(uint4*)(etb + code * 128 + ((ch * 16) ^ ((code & 7) << 4))) = v;
            }
            __syncthreads();

#pragma unroll
            for (int j = 0; j < 2; ++j) {
                const int kb  = dc * 128 + j * 64 + g * 16;
                const int kbl = j * 64 + g * 16;
                short8 a[4], b[4];
#pragma unroll
                for (int rf = 0; rf < 4; ++rf) {
                    int row = wr * 64 + rf * 16 + col;
                    a[rf] = *(const short8*)(zhb + row * 512 + (kb ^ asw));
                }
#pragma unroll
                for (int cf = 0; cf < 4; ++cf) {
                    int code = wc * 64 + cf * 16 + col;
                    b[cf] = *(const short8*)(etb + code * 128 + (kbl ^ asw));
                }
#pragma unroll
                for (int rf = 0; rf < 4; ++rf)
#pragma unroll
                    for (int cf = 0; cf < 4; ++cf)
                        acc[rf][cf] = __builtin_amdgcn_mfma_f32_16x16x32_bf16(
                            a[rf], b[cf], acc[rf][cf], 0, 0, 0);
            }
            __syncthreads();
        }

        // ---- epilogue: s = esq - 2*cross ; tile min ; candidate append (score+idx) ----
#pragma unroll
        for (int rf = 0; rf < 4; ++rf)
#pragma unroll
            for (int cf = 0; cf < 4; ++cf)
#pragma unroll
                for (int i = 0; i < 4; ++i)
                    acc[rf][cf][i] = fmaf(-2.0f, acc[rf][cf][i], esqv[cf]);

#pragma unroll
        for (int rf = 0; rf < 4; ++rf)
#pragma unroll
            for (int i = 0; i < 4; ++i) {
                float m = fminf(fminf(acc[rf][0][i], acc[rf][1][i]),
                                fminf(acc[rf][2][i], acc[rf][3][i]));
                m = fminf(m, __shfl_xor(m, 1, 64));
                m = fminf(m, __shfl_xor(m, 2, 64));
                m = fminf(m, __shfl_xor(m, 4, 64));
                m = fminf(m, __shfl_xor(m, 8, 64));
                if (col == 0) part[wc * 128 + wr * 64 + rf * 16 + g * 4 + i] = m;
            }
        __syncthreads();
        if (t < 128) {
            float m = fminf(fminf(part[0 * 128 + t], part[1 * 128 + t]),
                            fminf(part[2 * 128 + t], part[3 * 128 + t]));
            m = fminf(m, rowmin[t]);
            rowmin[t] = m;
            thr[t] = m + MARGIN;
        }
        __syncthreads();
#pragma unroll
        for (int rf = 0; rf < 4; ++rf)
#pragma unroll
            for (int i = 0; i < 4; ++i) {
                int row = wr * 64 + rf * 16 + g * 4 + i;
                float tv = thr[row];
#pragma unroll
                for (int cf = 0; cf < 4; ++cf) {
                    if (acc[rf][cf][i] <= tv) {
                        unsigned int pos = atomicAdd(&cnt[row], 1u);
                        if (pos < 16u) {
                            cand_s[row * 16 + pos] = acc[rf][cf][i];
                            cand_i[row * 16 + pos] = (unsigned int)(c0 + wc * 64 + cf * 16 + col);
                        }
                    }
                }
            }
        __syncthreads();
    }

    // ---- final prune against final rowmin; decide winner or flag ----
    if (t < 128) {
        float tf = __fadd_rn(rowmin[t], MARGIN);
        unsigned int c  = cnt[t];
        unsigned int cc = c < 16u ? c : 16u;
        unsigned int surv[8];
        int sc = 0;
        for (unsigned int i = 0; i < cc; ++i) {
            if (cand_s[t * 16 + i] <= tf) {
                if (sc < 8) surv[sc] = cand_i[t * 16 + i];
                ++sc;
            }
        }
        unsigned int row_g = (unsigned int)(r0 + t);
        unsigned int win = surv[0];
        if (c > 16u || sc > 8) {
            unsigned int pos = atomicAdd(flag_cnt, 1u);
            flag_list[pos] = row_g;                       // mode 0 = full scan
        } else if (sc >= 2) {
            unsigned int pos = atomicAdd(flag_cnt, 1u);
            flag_list[pos] = row_g | ((unsigned int)sc << 20);
            for (int j = 0; j < sc; ++j) cand_g[(size_t)row_g * 8 + j] = surv[j];
        }
        kst2[t] = win;
    }
    __syncthreads();

    // ---- gather approx winners (resolve overwrites flagged rows) ----
    const float4* E4 = (const float4*)E;
    float4* O4 = (float4*)out;
#pragma unroll
    for (int q = 0; q < 16; ++q) {
        int idx = t + 512 * q;
        int row = idx >> 6, f4 = idx & 63;
        unsigned int k = kst2[row];
        O4[(size_t)(r0 + row) * 64 + f4] = E4[(size_t)k * 64 + f4];
    }
}

// ---------------- resolve: one wave per flagged row, round-1-exact arithmetic --------------
__device__ __forceinline__ u64 exact_key(const float4* __restrict__ zr4,
                                         const float* __restrict__ E,
                                         const float* __restrict__ esq,
                                         float zs, unsigned int k) {
    const float4* er4 = (const float4*)(E + (size_t)k * D_);
    float c = 0.f;
#pragma unroll 8
    for (int q = 0; q < 64; ++q) {
        float4 a = zr4[q], b = er4[q];
        c = fmaf(a.x, b.x, c);
        c = fmaf(a.y, b.y, c);
        c = fmaf(a.z, b.z, c);
        c = fmaf(a.w, b.w, c);
    }
    float dist = __fadd_rn(__fsub_rn(zs, __fmul_rn(2.0f, c)), esq[k]);
    return ((u64)__float_as_uint(dist) << 32) | (u64)k;
}

__global__ __launch_bounds__(256)
void resolve_kernel(const float* __restrict__ Z, const float* __restrict__ E,
                    const float* __restrict__ esq, const unsigned int* __restrict__ flag_cnt,
                    const unsigned int* __restrict__ flag_list,
                    const unsigned int* __restrict__ cand_g, float* __restrict__ out) {
    const int lane = threadIdx.x & 63;
    const int wid  = (blockIdx.x * 256 + threadIdx.x) >> 6;
    const int nw   = (gridDim.x * 256) >> 6;
    const unsigned int nf = flag_cnt[0];

    const float4* E4 = (const float4*)E;
    float4* O4 = (float4*)out;

    for (unsigned int i = wid; i < nf; i += nw) {
        unsigned int e    = flag_list[i];
        unsigned int row  = e & 0xFFFFFu;
        unsigned int mode = e >> 20;
        const float* zr = Z + (size_t)row * D_;
        const float4* zr4 = (const float4*)zr;
        float zs = np_pairwise_sq_256(zr);

        u64 best = ~0ull;
        if (mode == 0u) {
            for (unsigned int k = lane; k < (unsigned int)K_; k += 64u) {
                u64 key = exact_key(zr4, E, esq, zs, k);
                if (key < best) best = key;
            }
        } else if ((unsigned int)lane < mode) {
            best = exact_key(zr4, E, esq, zs, cand_g[(size_t)row * 8 + lane]);
        }
#pragma unroll
        for (int off = 32; off >= 1; off >>= 1) {
            u64 o = __shfl_xor(best, off, 64);
            if (o < best) best = o;
        }
        unsigned int kw = (unsigned int)(best & 0xffffffffu);
        O4[(size_t)row * 64 + lane] = E4[(size_t)kw * 64 + lane];
    }
}

extern "C" void kernel_launch(void* const* d_in, const int* in_sizes, int n_in,
                              void* d_out, int out_size, void* d_ws, size_t ws_size,
                              hipStream_t stream) {
    const float* Z = (const float*)d_in[0];
    const float* E = (const float*)d_in[1];
    float* out = (float*)d_out;

    // workspace layout (~5.05 MB)
    float*          esq       = (float*)d_ws;                                  // 4 KB
    unsigned short* Eh        = (unsigned short*)((char*)d_ws + 4096);         // 512 KB
    unsigned int*   flag_cnt  = (unsigned int*)((char*)d_ws + 528384);         // 256 B
    unsigned int*   flag_list = (unsigned int*)((char*)d_ws + 528640);         // 512 KB
    unsigned int*   cand_g    = (unsigned int*)((char*)d_ws + 1052928);        // 4 MB

    prep_kernel<<<K_ / 64, 64, 0, stream>>>(E, esq, Eh, flag_cnt);

    const int SMEM = 118272 + 512;
    hipFuncSetAttribute((const void*)vq_main,
                        hipFuncAttributeMaxDynamicSharedMemorySize, SMEM);
    vq_main<<<N_ / 128, 512, SMEM, stream>>>(Z, Eh, esq, E,
                                             flag_cnt, flag_list, cand_g, out);

    resolve_kernel<<<1024, 256, 0, stream>>>(Z, E, esq, flag_cnt, flag_list, cand_g, out);
}

// Round 5
// 313.347 us; speedup vs baseline: 10.0848x; 1.2451x over previous
//
#include <hip/hip_runtime.h>
#include <stdint.h>

typedef unsigned long long u64;
typedef unsigned int u32;
typedef unsigned short u16;

#define D_      256
#define K_      1024
#define N_      131072
#define RB      64
#define MARGIN  0.024f

using short8 = __attribute__((ext_vector_type(8))) short;
using f32x4  = __attribute__((ext_vector_type(4))) float;

__device__ __forceinline__ u16 f2bf(float f) {
    u32 x = __float_as_uint(f);
    return (u16)((x + 0x7fffu + ((x >> 16) & 1u)) >> 16);
}
__device__ __forceinline__ float sqr_rn(float x) { return __fmul_rn(x, x); }

// numpy pairwise sum of squares over 256 elements (bitwise identical to rounds 1/3 passing code)
__device__ __forceinline__ float np_pairwise_sq_256(const float* p) {
    float tot[2];
#pragma unroll
    for (int blk = 0; blk < 2; ++blk) {
        const float* q = p + blk * 128;
        float r[8];
#pragma unroll
        for (int j = 0; j < 8; ++j) r[j] = sqr_rn(q[j]);
        for (int i = 8; i < 128; i += 8) {
#pragma unroll
            for (int j = 0; j < 8; ++j) r[j] = __fadd_rn(r[j], sqr_rn(q[i + j]));
        }
        tot[blk] = __fadd_rn(__fadd_rn(__fadd_rn(r[0], r[1]), __fadd_rn(r[2], r[3])),
                             __fadd_rn(__fadd_rn(r[4], r[5]), __fadd_rn(r[6], r[7])));
    }
    return __fadd_rn(tot[0], tot[1]);
}

// ---------------- prep 1: esq (np-pairwise f32) + zero flag counter ----------------
__global__ __launch_bounds__(256)
void prep_esq(const float* __restrict__ E, float* __restrict__ esq,
              u32* __restrict__ flag_cnt) {
    int code = blockIdx.x * 256 + threadIdx.x;
    if (code == 0) flag_cnt[0] = 0u;
    esq[code] = np_pairwise_sq_256(E + (size_t)code * D_);
}

// ---------------- prep 2: E image, (-2*E) in bf16, d-major tiled for linear LDS staging ----
// tile (ct 0..3, dc 0..7) = 16KB: [dchunk g 0..3][code-in-tile 0..255] x 16B (8 bf16 k-elems)
__global__ __launch_bounds__(256)
void prep_img(const float* __restrict__ E, u16* __restrict__ EhImg) {
    int idx  = blockIdx.x * 256 + threadIdx.x;   // 8192 tasks
    int code = idx >> 3, dc = idx & 7;
    int ct = code >> 8, lc = code & 255;
    const float4* e4 = (const float4*)(E + (size_t)code * D_ + dc * 32);
    char* tile = (char*)EhImg + ((size_t)(ct * 8 + dc) << 14);
#pragma unroll
    for (int dch = 0; dch < 4; ++dch) {
        float4 v0 = e4[dch * 2], v1 = e4[dch * 2 + 1];
        u32 a = (u32)f2bf(-2.0f * v0.x) | ((u32)f2bf(-2.0f * v0.y) << 16);
        u32 b = (u32)f2bf(-2.0f * v0.z) | ((u32)f2bf(-2.0f * v0.w) << 16);
        u32 c = (u32)f2bf(-2.0f * v1.x) | ((u32)f2bf(-2.0f * v1.y) << 16);
        u32 d = (u32)f2bf(-2.0f * v1.z) | ((u32)f2bf(-2.0f * v1.w) << 16);
        *(uint4*)(tile + (dch * 256 + lc) * 16) = make_uint4(a, b, c, d);
    }
}

// ---------------- main: 64 rows x 1024 codes per block, 8 waves (2r x 4c) ----------------
// E staged via reg (global->reg->ds_write), double-buffered, 1 barrier per k-step.
__global__ __launch_bounds__(512, 4)
void vq_main(const float* __restrict__ Z, const u16* __restrict__ EhImg,
             const float* __restrict__ esq_g, const float* __restrict__ E,
             u32* __restrict__ flag_cnt, u32* __restrict__ flag_list,
             u32* __restrict__ cand_g, float* __restrict__ out) {
    extern __shared__ char smem[];
    char*  zhb    = smem;                      // 32768: [64 rows][512B], byte-xor swizzle
    char*  etb0   = smem + 32768;              // 16384
    char*  etb1   = smem + 49152;              // 16384
    float* part   = (float*)(smem + 65536);    // 1024
    float* rowmin = (float*)(smem + 66560);    // 256
    u32*   cnt    = (u32*)(smem + 66816);      // 256
    float* cand_s = (float*)(smem + 67072);    // 4096
    u32*   cand_i = (u32*)(smem + 71168);      // 4096
    u32*   kst    = (u32*)(smem + 75264);      // 256   (total 75520 B)

    const int t    = threadIdx.x;
    const int lane = t & 63;
    const int wv   = t >> 6;
    const int wr   = wv >> 2;        // 0..1: 32-row band
    const int wc   = wv & 3;         // 0..3: 64-code band
    const int col  = lane & 15;
    const int g    = lane >> 4;      // k-slice
    const int r0   = blockIdx.x * RB;
    const int asw  = (lane & 7) << 4;

    if (t < RB) { rowmin[t] = 3.0e38f; cnt[t] = 0u; }

    // ---- stage z tile (f32 -> bf16, row-major 512B rows, xor swizzle) + E tile 0 ----
    const uint4* EI = (const uint4*)EhImg;     // 1024 uint4 per 16KB tile
    uint4 s0 = EI[t], s1 = EI[t + 512];
    const float4* Z4 = (const float4*)(Z + (size_t)r0 * D_);
#pragma unroll
    for (int q = 0; q < 8; ++q) {
        int idx = t + 512 * q;
        int row = idx >> 6, c4 = idx & 63;
        float4 v = Z4[(size_t)row * 64 + c4];
        u32 lo = (u32)f2bf(v.x) | ((u32)f2bf(v.y) << 16);
        u32 hi = (u32)f2bf(v.z) | ((u32)f2bf(v.w) << 16);
        int boff = (c4 * 8) ^ ((row & 7) << 4);
        *(uint2*)(zhb + row * 512 + boff) = make_uint2(lo, hi);
    }
    *(uint4*)(etb0 + t * 16) = s0;
    *(uint4*)(etb0 + 8192 + t * 16) = s1;
    __syncthreads();

    f32x4 acc[2][4];

    for (int tl = 0; tl < 32; ++tl) {
        const int dc = tl & 7;
        char* cur = (tl & 1) ? etb1 : etb0;
        char* nxt = (tl & 1) ? etb0 : etb1;

        if (dc == 0) {
            const int ct = tl >> 3;
#pragma unroll
            for (int cf = 0; cf < 4; ++cf) {
                float ev = esq_g[ct * 256 + wc * 64 + cf * 16 + col];
#pragma unroll
                for (int rf = 0; rf < 2; ++rf)
                    acc[rf][cf] = (f32x4){ev, ev, ev, ev};   // esq baked as C-in
            }
        }
        // issue next-tile global loads early (consumed by ds_write below)
        uint4 p0, p1;
        const bool pf = (tl < 31);
        if (pf) {
            const uint4* src = (const uint4*)((const char*)EhImg + ((size_t)(tl + 1) << 14));
            p0 = src[t]; p1 = src[t + 512];
        }

        const int kb = dc * 64 + g * 16;
        short8 a[2], b[4];
#pragma unroll
        for (int rf = 0; rf < 2; ++rf) {
            int row = wr * 32 + rf * 16 + col;
            a[rf] = *(const short8*)(zhb + row * 512 + (kb ^ asw));
        }
        const char* bbase = cur + g * 4096 + wc * 1024 + col * 16;
#pragma unroll
        for (int cf = 0; cf < 4; ++cf)
            b[cf] = *(const short8*)(bbase + cf * 256);
#pragma unroll
        for (int rf = 0; rf < 2; ++rf)
#pragma unroll
            for (int cf = 0; cf < 4; ++cf)
                acc[rf][cf] = __builtin_amdgcn_mfma_f32_16x16x32_bf16(
                    a[rf], b[cf], acc[rf][cf], 0, 0, 0);

        if (pf) {
            *(uint4*)(nxt + t * 16) = p0;
            *(uint4*)(nxt + 8192 + t * 16) = p1;
        }
        __syncthreads();

        if (dc == 7) {
            const int ct = tl >> 3;
            // ---- per-ct epilogue: scores are in acc directly ----
#pragma unroll
            for (int rf = 0; rf < 2; ++rf)
#pragma unroll
                for (int i = 0; i < 4; ++i) {
                    float m = fminf(fminf(acc[rf][0][i], acc[rf][1][i]),
                                    fminf(acc[rf][2][i], acc[rf][3][i]));
                    m = fminf(m, __shfl_xor(m, 1, 64));
                    m = fminf(m, __shfl_xor(m, 2, 64));
                    m = fminf(m, __shfl_xor(m, 4, 64));
                    m = fminf(m, __shfl_xor(m, 8, 64));
                    if (col == 0) part[wc * 64 + wr * 32 + rf * 16 + g * 4 + i] = m;
                }
            __syncthreads();
            if (t < RB)
                rowmin[t] = fminf(rowmin[t],
                    fminf(fminf(part[t], part[64 + t]), fminf(part[128 + t], part[192 + t])));
            __syncthreads();
#pragma unroll
            for (int rf = 0; rf < 2; ++rf)
#pragma unroll
                for (int i = 0; i < 4; ++i) {
                    int row = wr * 32 + rf * 16 + g * 4 + i;
                    float tv = __fadd_rn(rowmin[row], MARGIN);
#pragma unroll
                    for (int cf = 0; cf < 4; ++cf) {
                        if (acc[rf][cf][i] <= tv) {
                            u32 pos = atomicAdd(&cnt[row], 1u);
                            if (pos < 16u) {
                                cand_s[row * 16 + pos] = acc[rf][cf][i];
                                cand_i[row * 16 + pos] =
                                    (u32)(ct * 256 + wc * 64 + cf * 16 + col);
                            }
                        }
                    }
                }
            // no trailing barrier: next k-step's barrier orders appends vs next reads
        }
    }
    __syncthreads();   // last ct's appends complete

    // ---- final prune vs final rowmin; decide winner or flag ----
    if (t < RB) {
        float tf = __fadd_rn(rowmin[t], MARGIN);
        u32 c  = cnt[t];
        u32 cc = c < 16u ? c : 16u;
        u32 surv[8];
        int sc = 0;
        for (u32 i = 0; i < cc; ++i) {
            if (cand_s[t * 16 + i] <= tf) {
                if (sc < 8) surv[sc] = cand_i[t * 16 + i];
                ++sc;
            }
        }
        u32 row_g = (u32)(r0 + t);
        u32 win = (sc > 0) ? surv[0] : 0u;
        if (c > 16u || sc > 8) {
            u32 pos = atomicAdd(flag_cnt, 1u);
            flag_list[pos] = row_g;                         // mode 0 = full scan
        } else if (sc >= 2) {
            u32 pos = atomicAdd(flag_cnt, 1u);
            flag_list[pos] = row_g | ((u32)sc << 20);
            for (int j = 0; j < sc; ++j) cand_g[(size_t)row_g * 8 + j] = surv[j];
        }
        kst[t] = win;
    }
    __syncthreads();

    // ---- gather winners (resolve overwrites flagged rows) ----
    const float4* E4 = (const float4*)E;
    float4* O4 = (float4*)out;
#pragma unroll
    for (int q = 0; q < 8; ++q) {
        int idx = t + 512 * q;
        int row = idx >> 6, f4 = idx & 63;
        u32 k = kst[row] & 1023u;
        O4[(size_t)(r0 + row) * 64 + f4] = E4[(size_t)k * 64 + f4];
    }
}

// ---------------- resolve: one wave per flagged row, round-1-exact arithmetic --------------
__device__ __forceinline__ u64 exact_key(const float4* __restrict__ zr4,
                                         const float* __restrict__ E,
                                         const float* __restrict__ esq,
                                         float zs, u32 k) {
    const float4* er4 = (const float4*)(E + (size_t)k * D_);
    float c = 0.f;
#pragma unroll 8
    for (int q = 0; q < 64; ++q) {
        float4 a = zr4[q], b = er4[q];
        c = fmaf(a.x, b.x, c);
        c = fmaf(a.y, b.y, c);
        c = fmaf(a.z, b.z, c);
        c = fmaf(a.w, b.w, c);
    }
    float dist = __fadd_rn(__fsub_rn(zs, __fmul_rn(2.0f, c)), esq[k]);
    return ((u64)__float_as_uint(dist) << 32) | (u64)k;
}

__global__ __launch_bounds__(256)
void resolve_kernel(const float* __restrict__ Z, const float* __restrict__ E,
                    const float* __restrict__ esq, const u32* __restrict__ flag_cnt,
                    const u32* __restrict__ flag_list,
                    const u32* __restrict__ cand_g, float* __restrict__ out) {
    const int lane = threadIdx.x & 63;
    const int wid  = (blockIdx.x * 256 + threadIdx.x) >> 6;
    const int nw   = (gridDim.x * 256) >> 6;
    const u32 nf = flag_cnt[0];

    const float4* E4 = (const float4*)E;
    float4* O4 = (float4*)out;

    for (u32 i = wid; i < nf; i += nw) {
        u32 e    = flag_list[i];
        u32 row  = e & 0xFFFFFu;
        u32 mode = e >> 20;
        const float* zr = Z + (size_t)row * D_;
        const float4* zr4 = (const float4*)zr;

        // exact np-pairwise zs, 16-lane-parallel, combine order bitwise = reference
        float r = 0.f;
        {
            int cidx = lane & 15, blk = cidx >> 3, j = cidx & 7;
            if (lane < 16) {
                const float* q = zr + blk * 128 + j;
                r = sqr_rn(q[0]);
                for (int ii = 8; ii < 128; ii += 8) r = __fadd_rn(r, sqr_rn(q[ii]));
            }
        }
        {
            float o = __shfl_xor(r, 1, 64);  r = __fadd_rn(r, o);
            o = __shfl_xor(r, 2, 64);        r = __fadd_rn(r, o);
            o = __shfl_xor(r, 4, 64);        r = __fadd_rn(r, o);
            o = __shfl_xor(r, 8, 64);        r = __fadd_rn(r, o);
        }
        float zs = __shfl(r, 0, 64);

        u64 best = ~0ull;
        if (mode == 0u) {
            for (u32 k = (u32)lane; k < (u32)K_; k += 64u) {
                u64 key = exact_key(zr4, E, esq, zs, k);
                if (key < best) best = key;
            }
        } else if ((u32)lane < mode) {
            best = exact_key(zr4, E, esq, zs, cand_g[(size_t)row * 8 + lane]);
        }
#pragma unroll
        for (int off = 32; off >= 1; off >>= 1) {
            u64 o = __shfl_xor(best, off, 64);
            if (o < best) best = o;
        }
        u32 kw = (u32)(best & 0xffffffffu);
        O4[(size_t)row * 64 + lane] = E4[(size_t)kw * 64 + lane];
    }
}

extern "C" void kernel_launch(void* const* d_in, const int* in_sizes, int n_in,
                              void* d_out, int out_size, void* d_ws, size_t ws_size,
                              hipStream_t stream) {
    const float* Z = (const float*)d_in[0];
    const float* E = (const float*)d_in[1];
    float* out = (float*)d_out;

    float* esq       = (float*)d_ws;                              // 4 KB
    u16*   EhImg     = (u16*)((char*)d_ws + 4096);                // 512 KB
    u32*   flag_cnt  = (u32*)((char*)d_ws + 528384);              // 256 B
    u32*   flag_list = (u32*)((char*)d_ws + 528640);              // 512 KB
    u32*   cand_g    = (u32*)((char*)d_ws + 1052928);             // 4 MB

    prep_esq<<<K_ / 256, 256, 0, stream>>>(E, esq, flag_cnt);
    prep_img<<<(K_ * 8) / 256, 256, 0, stream>>>(E, EhImg);

    const int SMEM = 75520;
    hipFuncSetAttribute((const void*)vq_main,
                        hipFuncAttributeMaxDynamicSharedMemorySize, SMEM);
    vq_main<<<N_ / RB, 512, SMEM, stream>>>(Z, EhImg, esq, E,
                                            flag_cnt, flag_list, cand_g, out);

    resolve_kernel<<<1024, 256, 0, stream>>>(Z, E, esq, flag_cnt, flag_list, cand_g, out);
}

// Round 6
// 208.321 us; speedup vs baseline: 15.1690x; 1.5042x over previous
//
#include <hip/hip_runtime.h>
#include <stdint.h>

typedef unsigned long long u64;
typedef unsigned int u32;
typedef unsigned short u16;

#define D_      256
#define K_      1024
#define N_      131072
#define RB      64
#define MARGIN  0.024f
#define CAP     32

using short8 = __attribute__((ext_vector_type(8))) short;
using f32x4  = __attribute__((ext_vector_type(4))) float;

__device__ __forceinline__ u16 f2bf(float f) {
    u32 x = __float_as_uint(f);
    return (u16)((x + 0x7fffu + ((x >> 16) & 1u)) >> 16);
}
__device__ __forceinline__ float sqr_rn(float x) { return __fmul_rn(x, x); }

// numpy pairwise sum of squares over 256 elements (bitwise identical to rounds 1/3/5)
__device__ __forceinline__ float np_pairwise_sq_256(const float* p) {
    float tot[2];
#pragma unroll
    for (int blk = 0; blk < 2; ++blk) {
        const float* q = p + blk * 128;
        float r[8];
#pragma unroll
        for (int j = 0; j < 8; ++j) r[j] = sqr_rn(q[j]);
        for (int i = 8; i < 128; i += 8) {
#pragma unroll
            for (int j = 0; j < 8; ++j) r[j] = __fadd_rn(r[j], sqr_rn(q[i + j]));
        }
        tot[blk] = __fadd_rn(__fadd_rn(__fadd_rn(r[0], r[1]), __fadd_rn(r[2], r[3])),
                             __fadd_rn(__fadd_rn(r[4], r[5]), __fadd_rn(r[6], r[7])));
    }
    return __fadd_rn(tot[0], tot[1]);
}

// ------- prep (merged): E image (-2E bf16, d-major) + esq (np-pairwise) + flag_cnt=0 -------
// image tile (ct 0..3, dc 0..7) = 16KB: [g 0..3][code-in-tile 0..255] x 16B (8 bf16 k-elems)
__global__ __launch_bounds__(256)
void prep_all(const float* __restrict__ E, u16* __restrict__ EhImg,
              float* __restrict__ esq, u32* __restrict__ flag_cnt) {
    int idx  = blockIdx.x * 256 + threadIdx.x;   // 8192 tasks
    if (idx == 0) flag_cnt[0] = 0u;
    int code = idx >> 3, dc = idx & 7;
    int ct = code >> 8, lc = code & 255;
    const float4* e4 = (const float4*)(E + (size_t)code * D_ + dc * 32);
    char* tile = (char*)EhImg + ((size_t)(ct * 8 + dc) << 14);
#pragma unroll
    for (int dch = 0; dch < 4; ++dch) {
        float4 v0 = e4[dch * 2], v1 = e4[dch * 2 + 1];
        u32 a = (u32)f2bf(-2.0f * v0.x) | ((u32)f2bf(-2.0f * v0.y) << 16);
        u32 b = (u32)f2bf(-2.0f * v0.z) | ((u32)f2bf(-2.0f * v0.w) << 16);
        u32 c = (u32)f2bf(-2.0f * v1.x) | ((u32)f2bf(-2.0f * v1.y) << 16);
        u32 d = (u32)f2bf(-2.0f * v1.z) | ((u32)f2bf(-2.0f * v1.w) << 16);
        *(uint4*)(tile + (dch * 256 + lc) * 16) = make_uint4(a, b, c, d);
    }
    if (dc == 0) esq[code] = np_pairwise_sq_256(E + (size_t)code * D_);
}

// ---------------- main: 64 rows x 1024 codes, 8 waves (2r x 4c), barrier-free k-loop ------
// z in LDS (read-only after one barrier); B-frags read directly from L2-resident EhImg,
// register double-buffered (depth 2). No ds_write / barrier / LDS-atomic in the k-loop.
__global__ __launch_bounds__(512, 4)
void vq_main(const float* __restrict__ Z, const u16* __restrict__ EhImg,
             const float* __restrict__ esq_g, const float* __restrict__ E,
             u32* __restrict__ flag_cnt, u32* __restrict__ flag_list,
             u32* __restrict__ cand_g, float* __restrict__ out) {
    extern __shared__ char smem[];
    char*  zhb    = smem;                      // 32768: [64 rows][512B], byte-xor swizzle
    float* part   = (float*)(smem + 32768);    // 1024
    float* rowmin = (float*)(smem + 33792);    // 256
    u32*   cnt    = (u32*)(smem + 34048);      // 256
    float* cand_s = (float*)(smem + 34304);    // 64*32*4 = 8192
    u32*   cand_i = (u32*)(smem + 42496);      // 8192
    u32*   kst    = (u32*)(smem + 50688);      // 256   (total 50944 B)

    const int t    = threadIdx.x;
    const int lane = t & 63;
    const int wv   = t >> 6;
    const int wr   = wv >> 2;        // 0..1: 32-row band
    const int wc   = wv & 3;         // 0..3: 64-code band
    const int col  = lane & 15;
    const int g    = lane >> 4;      // k-slice
    const int r0   = blockIdx.x * RB;
    const int asw  = (lane & 7) << 4;

    if (t < RB) { rowmin[t] = 3.0e38f; cnt[t] = 0u; }

    // ---- stage z tile (f32 -> bf16, row-major 512B rows, xor swizzle) ----
    const float4* Z4 = (const float4*)(Z + (size_t)r0 * D_);
#pragma unroll
    for (int q = 0; q < 8; ++q) {
        int idx = t + 512 * q;
        int row = idx >> 6, c4 = idx & 63;
        float4 v = Z4[(size_t)row * 64 + c4];
        u32 lo = (u32)f2bf(v.x) | ((u32)f2bf(v.y) << 16);
        u32 hi = (u32)f2bf(v.z) | ((u32)f2bf(v.w) << 16);
        int boff = (c4 * 8) ^ ((row & 7) << 4);
        *(uint2*)(zhb + row * 512 + boff) = make_uint2(lo, hi);
    }
    __syncthreads();   // z visible; LDS read-only from here until epilogues

    const char* ebase = (const char*)EhImg;
    const int   loff  = g * 4096 + wc * 1024 + col * 16;   // per-lane offset within a tile

    f32x4 acc[2][4];
    short8 bv[2][4];

    for (int ct = 0; ct < 4; ++ct) {
        // acc init: esq baked as C-in
#pragma unroll
        for (int cf = 0; cf < 4; ++cf) {
            float ev = esq_g[ct * 256 + wc * 64 + cf * 16 + col];
#pragma unroll
            for (int rf = 0; rf < 2; ++rf)
                acc[rf][cf] = (f32x4){ev, ev, ev, ev};
        }
        // B prologue: tiles (ct,0) and (ct,1)
        {
            const char* t0 = ebase + ((size_t)(ct * 8 + 0) << 14) + loff;
            const char* t1 = ebase + ((size_t)(ct * 8 + 1) << 14) + loff;
#pragma unroll
            for (int cf = 0; cf < 4; ++cf) {
                bv[0][cf] = *(const short8*)(t0 + cf * 256);
                bv[1][cf] = *(const short8*)(t1 + cf * 256);
            }
        }
#pragma unroll
        for (int dc = 0; dc < 8; ++dc) {
            const int kb = dc * 64 + g * 16;
            short8 a[2];
#pragma unroll
            for (int rf = 0; rf < 2; ++rf) {
                int row = wr * 32 + rf * 16 + col;
                a[rf] = *(const short8*)(zhb + row * 512 + (kb ^ asw));
            }
#pragma unroll
            for (int rf = 0; rf < 2; ++rf)
#pragma unroll
                for (int cf = 0; cf < 4; ++cf)
                    acc[rf][cf] = __builtin_amdgcn_mfma_f32_16x16x32_bf16(
                        a[rf], bv[dc & 1][cf], acc[rf][cf], 0, 0, 0);
            if (dc < 6) {
                const char* tn = ebase + ((size_t)(ct * 8 + dc + 2) << 14) + loff;
#pragma unroll
                for (int cf = 0; cf < 4; ++cf)
                    bv[dc & 1][cf] = *(const short8*)(tn + cf * 256);
            }
        }

        // ---- per-ct epilogue: scores are in acc directly ----
#pragma unroll
        for (int rf = 0; rf < 2; ++rf)
#pragma unroll
            for (int i = 0; i < 4; ++i) {
                float m = fminf(fminf(acc[rf][0][i], acc[rf][1][i]),
                                fminf(acc[rf][2][i], acc[rf][3][i]));
                m = fminf(m, __shfl_xor(m, 1, 64));
                m = fminf(m, __shfl_xor(m, 2, 64));
                m = fminf(m, __shfl_xor(m, 4, 64));
                m = fminf(m, __shfl_xor(m, 8, 64));
                if (col == 0) part[wc * 64 + wr * 32 + rf * 16 + g * 4 + i] = m;
            }
        __syncthreads();
        if (t < RB)
            rowmin[t] = fminf(rowmin[t],
                fminf(fminf(part[t], part[64 + t]), fminf(part[128 + t], part[192 + t])));
        __syncthreads();
#pragma unroll
        for (int rf = 0; rf < 2; ++rf)
#pragma unroll
            for (int i = 0; i < 4; ++i) {
                int row = wr * 32 + rf * 16 + g * 4 + i;
                float tv = __fadd_rn(rowmin[row], MARGIN);
#pragma unroll
                for (int cf = 0; cf < 4; ++cf) {
                    if (acc[rf][cf][i] <= tv) {
                        u32 pos = atomicAdd(&cnt[row], 1u);
                        if (pos < (u32)CAP) {
                            cand_s[row * CAP + pos] = acc[rf][cf][i];
                            cand_i[row * CAP + pos] =
                                (u32)(ct * 256 + wc * 64 + cf * 16 + col);
                        }
                    }
                }
            }
        __syncthreads();   // appends done before next ct's rowmin update / final prune
    }

    // ---- final prune vs final rowmin; decide winner or flag ----
    if (t < RB) {
        float tf = __fadd_rn(rowmin[t], MARGIN);
        u32 c  = cnt[t];
        u32 cc = c < (u32)CAP ? c : (u32)CAP;
        u32 surv[8];
        int sc = 0;
        for (u32 i = 0; i < cc; ++i) {
            if (cand_s[t * CAP + i] <= tf) {
                if (sc < 8) surv[sc] = cand_i[t * CAP + i];
                ++sc;
            }
        }
        u32 row_g = (u32)(r0 + t);
        u32 win = (sc > 0) ? surv[0] : 0u;
        if (c > (u32)CAP || sc > 8) {
            u32 pos = atomicAdd(flag_cnt, 1u);
            flag_list[pos] = row_g;                         // mode 0 = full scan
        } else if (sc >= 2) {
            u32 pos = atomicAdd(flag_cnt, 1u);
            flag_list[pos] = row_g | ((u32)sc << 20);
            for (int j = 0; j < sc; ++j) cand_g[(size_t)row_g * 8 + j] = surv[j];
        }
        kst[t] = win;
    }
    __syncthreads();

    // ---- gather winners (resolve overwrites flagged rows) ----
    const float4* E4 = (const float4*)E;
    float4* O4 = (float4*)out;
#pragma unroll
    for (int q = 0; q < 8; ++q) {
        int idx = t + 512 * q;
        int row = idx >> 6, f4 = idx & 63;
        u32 k = kst[row] & 1023u;
        O4[(size_t)(r0 + row) * 64 + f4] = E4[(size_t)k * 64 + f4];
    }
}

// ---------------- resolve: one wave per flagged row; 8 lanes per candidate dot ------------
__device__ __forceinline__ u64 exact_key_serial(const float4* __restrict__ zr4,
                                                const float* __restrict__ E,
                                                const float* __restrict__ esq,
                                                float zs, u32 k) {
    const float4* er4 = (const float4*)(E + (size_t)k * D_);
    float c = 0.f;
#pragma unroll 8
    for (int q = 0; q < 64; ++q) {
        float4 a = zr4[q], b = er4[q];
        c = fmaf(a.x, b.x, c);
        c = fmaf(a.y, b.y, c);
        c = fmaf(a.z, b.z, c);
        c = fmaf(a.w, b.w, c);
    }
    float dist = __fadd_rn(__fsub_rn(zs, __fmul_rn(2.0f, c)), esq[k]);
    return ((u64)__float_as_uint(dist) << 32) | (u64)k;
}

__global__ __launch_bounds__(256)
void resolve_kernel(const float* __restrict__ Z, const float* __restrict__ E,
                    const float* __restrict__ esq, const u32* __restrict__ flag_cnt,
                    const u32* __restrict__ flag_list,
                    const u32* __restrict__ cand_g, float* __restrict__ out) {
    const int lane = threadIdx.x & 63;
    const int wid  = (blockIdx.x * 256 + threadIdx.x) >> 6;
    const int nw   = (gridDim.x * 256) >> 6;
    const u32 nf = flag_cnt[0];

    const int grp = lane >> 3, sub = lane & 7;
    const float4* E4 = (const float4*)E;
    float4* O4 = (float4*)out;

    for (u32 i = wid; i < nf; i += nw) {
        u32 e    = flag_list[i];
        u32 row  = e & 0xFFFFFu;
        u32 mode = e >> 20;
        const float* zr = Z + (size_t)row * D_;
        const float4* zr4 = (const float4*)zr;

        // np-pairwise zs, 16-lane-parallel, combine order bitwise = reference (proven r3/r5)
        float r = 0.f;
        {
            int cidx = lane & 15, blk = cidx >> 3, j = cidx & 7;
            if (lane < 16) {
                const float* q = zr + blk * 128 + j;
                r = sqr_rn(q[0]);
                for (int ii = 8; ii < 128; ii += 8) r = __fadd_rn(r, sqr_rn(q[ii]));
            }
        }
        {
            float o = __shfl_xor(r, 1, 64);  r = __fadd_rn(r, o);
            o = __shfl_xor(r, 2, 64);        r = __fadd_rn(r, o);
            o = __shfl_xor(r, 4, 64);        r = __fadd_rn(r, o);
            o = __shfl_xor(r, 8, 64);        r = __fadd_rn(r, o);
        }
        float zs = __shfl(r, 0, 64);

        u64 best = ~0ull;
        if (mode == 0u) {
            for (u32 k = (u32)lane; k < (u32)K_; k += 64u) {
                u64 key = exact_key_serial(zr4, E, esq, zs, k);
                if (key < best) best = key;
            }
        } else {
            // 8 lanes per candidate: lane sub covers elems sub*32..sub*32+31
            if ((u32)grp < mode) {
                u32 k = cand_g[(size_t)row * 8 + grp];
                const float4* er4 = (const float4*)(E + (size_t)k * D_);
                float c = 0.f;
#pragma unroll
                for (int q = 0; q < 8; ++q) {
                    float4 a = zr4[sub * 8 + q], b = er4[sub * 8 + q];
                    c = fmaf(a.x, b.x, c);
                    c = fmaf(a.y, b.y, c);
                    c = fmaf(a.z, b.z, c);
                    c = fmaf(a.w, b.w, c);
                }
                // tree-reduce within the 8-lane group (deterministic)
                c = __fadd_rn(c, __shfl_xor(c, 1, 64));
                c = __fadd_rn(c, __shfl_xor(c, 2, 64));
                c = __fadd_rn(c, __shfl_xor(c, 4, 64));
                float dist = __fadd_rn(__fsub_rn(zs, __fmul_rn(2.0f, c)), esq[k]);
                best = ((u64)__float_as_uint(dist) << 32) | (u64)k;
            }
            // min across groups
            {
                u64 o = __shfl_xor(best, 8, 64);  if (o < best) best = o;
                o = __shfl_xor(best, 16, 64);     if (o < best) best = o;
                o = __shfl_xor(best, 32, 64);     if (o < best) best = o;
            }
        }
        if (mode == 0u) {
#pragma unroll
            for (int off = 32; off >= 1; off >>= 1) {
                u64 o = __shfl_xor(best, off, 64);
                if (o < best) best = o;
            }
        }
        u32 kw = (u32)(best & 0xffffffffu);
        O4[(size_t)row * 64 + lane] = E4[(size_t)kw * 64 + lane];
    }
}

extern "C" void kernel_launch(void* const* d_in, const int* in_sizes, int n_in,
                              void* d_out, int out_size, void* d_ws, size_t ws_size,
                              hipStream_t stream) {
    const float* Z = (const float*)d_in[0];
    const float* E = (const float*)d_in[1];
    float* out = (float*)d_out;

    float* esq       = (float*)d_ws;                              // 4 KB
    u16*   EhImg     = (u16*)((char*)d_ws + 4096);                // 512 KB
    u32*   flag_cnt  = (u32*)((char*)d_ws + 528384);              // 256 B
    u32*   flag_list = (u32*)((char*)d_ws + 528640);              // 512 KB
    u32*   cand_g    = (u32*)((char*)d_ws + 1052928);             // 4 MB

    prep_all<<<(K_ * 8) / 256, 256, 0, stream>>>(E, EhImg, esq, flag_cnt);

    const int SMEM = 50944;
    hipFuncSetAttribute((const void*)vq_main,
                        hipFuncAttributeMaxDynamicSharedMemorySize, SMEM);
    vq_main<<<N_ / RB, 512, SMEM, stream>>>(Z, EhImg, esq, E,
                                            flag_cnt, flag_list, cand_g, out);

    resolve_kernel<<<1024, 256, 0, stream>>>(Z, E, esq, flag_cnt, flag_list, cand_g, out);
}